// Round 1
// baseline (313.599 us; speedup 1.0000x reference)
//
#include <hip/hip_runtime.h>

// Advect: minmod-limited flux stencil along last axis.
// L = 8192 (ghost-padded), OUT = L-4 = 8188 per row, rows = B*M = 4096.
//
// main[k] = net[k] - net[k+1]
// net[j]  = fm(j) + fp(j)
//   fm(j) = (v[j+2] >= 0 || j == OUT) ? 0 : F[j+2] - hs[j+1]
//   fp(j) = (v[j+1] <= 0 || j == 0)   ? 0 : F[j+1] + hs[j]
//   hs(i) = 0.5 * minmod3( 2*(F[i+1]-F[i]), 0.5*(F[i+2]-F[i]), 2*(F[i+2]-F[i+1]) )
//         = minmod3( D[i], 0.25*(D[i]+D[i+1]), D[i+1] )   [positive homogeneity]
//   F[i]  = rho[i] * v[i],  D[i] = F[i+1] - F[i]
//
// v2: 8 outputs/thread (3x float4 halo loads per input, redundancy 1.5x vs 2.0x),
//     diff-reuse minmod form. Tail group (1 per row) degenerates to 4 outputs.

__device__ __forceinline__ float minmod3(float a, float b, float c) {
    float mn = fminf(fminf(a, b), c);
    float mx = fmaxf(fmaxf(a, b), c);
    return (mn < 0.0f) ? fminf(mx, 0.0f) : mn;
}

__global__ __launch_bounds__(256) void advect_kernel(
    const float* __restrict__ rho, const float* __restrict__ v,
    float* __restrict__ out, int L, int OUT, int GP8)
{
    int g = blockIdx.x * blockDim.x + threadIdx.x;   // group of 8 outputs
    if (g >= GP8) return;
    long row = blockIdx.y;
    const float* r  = rho + row * (long)L;
    const float* vp = v   + row * (long)L;
    int k0 = g * 8;
    bool full = (k0 + 8 <= OUT);   // full 8-output group needs F[k0..k0+11]

    // 12-wide halo load: outputs k0..k0+7 need indices k0..k0+11 (float4-aligned)
    float4 ra = *(const float4*)(r  + k0);
    float4 rb = *(const float4*)(r  + k0 + 4);
    float4 va = *(const float4*)(vp + k0);
    float4 vb = *(const float4*)(vp + k0 + 4);
    float4 rc, vc;
    if (full) {
        rc = *(const float4*)(r  + k0 + 8);
        vc = *(const float4*)(vp + k0 + 8);
    } else {
        // tail (k0 = 8184): only 4 outputs valid; duplicate to keep regs finite.
        rc = rb; vc = vb;
    }

    float V[12] = {va.x,va.y,va.z,va.w, vb.x,vb.y,vb.z,vb.w, vc.x,vc.y,vc.z,vc.w};
    float R[12] = {ra.x,ra.y,ra.z,ra.w, rb.x,rb.y,rb.z,rb.w, rc.x,rc.y,rc.z,rc.w};
    float F[12];
#pragma unroll
    for (int i = 0; i < 12; ++i) F[i] = R[i] * V[i];

    // forward differences, shared between adjacent hs
    float D[11];
#pragma unroll
    for (int i = 0; i < 11; ++i) D[i] = F[i+1] - F[i];

    // half-slope hs[i] ~ global index k0+i, i in [0,9]
    float hs[10];
#pragma unroll
    for (int i = 0; i < 10; ++i)
        hs[i] = minmod3(D[i], 0.25f * (D[i] + D[i+1]), D[i+1]);

    // net[j] ~ global index k0+j, j in [0,8]
    float net[9];
#pragma unroll
    for (int j = 0; j < 9; ++j) {
        int gj = k0 + j;
        float fm = (V[j+2] >= 0.0f || gj == OUT) ? 0.0f : (F[j+2] - hs[j+1]);
        float fp = (V[j+1] <= 0.0f || gj == 0)   ? 0.0f : (F[j+1] + hs[j]);
        net[j] = fm + fp;
    }

    float* op = out + row * (long)OUT + k0;
    float4 o0;
    o0.x = net[0] - net[1];
    o0.y = net[1] - net[2];
    o0.z = net[2] - net[3];
    o0.w = net[3] - net[4];
    *(float4*)op = o0;
    if (full) {
        float4 o1;
        o1.x = net[4] - net[5];
        o1.y = net[5] - net[6];
        o1.z = net[6] - net[7];
        o1.w = net[7] - net[8];
        *(float4*)(op + 4) = o1;
    }
}

extern "C" void kernel_launch(void* const* d_in, const int* in_sizes, int n_in,
                              void* d_out, int out_size, void* d_ws, size_t ws_size,
                              hipStream_t stream) {
    const float* rho = (const float*)d_in[0];
    const float* v   = (const float*)d_in[1];
    float* out = (float*)d_out;

    const int L    = 8192;
    const int rows = in_sizes[0] / L;   // B*M = 4096
    const int OUT  = L - 4;             // 8188
    const int GP8  = (OUT + 7) / 8;     // 1024 groups of 8 per row

    dim3 block(256);
    dim3 grid((GP8 + 255) / 256, rows); // (4, 4096)
    hipLaunchKernelGGL(advect_kernel, grid, block, 0, stream,
                       rho, v, out, L, OUT, GP8);
}